// Round 1
// baseline (401.535 us; speedup 1.0000x reference)
//
#include <hip/hip_runtime.h>
#include <stdint.h>
#include <stddef.h>

typedef __attribute__((ext_vector_type(8))) short bf16x8;
typedef __attribute__((ext_vector_type(4))) short short4v;
typedef __attribute__((ext_vector_type(4))) float f32x4;

#define MFMA16(a, b, c) __builtin_amdgcn_mfma_f32_16x16x32_bf16((a), (b), (c), 0, 0, 0)

__device__ __forceinline__ short f2bf(float f) {
    uint32_t u = __builtin_bit_cast(uint32_t, f);
    u = (u + 0x7FFFu + ((u >> 16) & 1u)) >> 16;
    return (short)(uint16_t)u;
}

// ---------------- weight fp32 -> bf16 (4 matrices of 1024x1024) ----------------
__global__ __launch_bounds__(256) void convw_kernel(
        const float* __restrict__ w0, const float* __restrict__ w1,
        const float* __restrict__ w2, const float* __restrict__ w3,
        short* __restrict__ dst) {
    const int z = blockIdx.z;
    const float* src = (z == 0) ? w0 : (z == 1) ? w1 : (z == 2) ? w2 : w3;
    const size_t i = ((size_t)blockIdx.x * 256 + threadIdx.x) * 4;
    f32x4 v = *(const f32x4*)(src + i);
    short4v o = { f2bf(v[0]), f2bf(v[1]), f2bf(v[2]), f2bf(v[3]) };
    *(short4v*)(dst + (size_t)z * 1048576 + i) = o;
}

// ---------------- log of multiplicities (4*2048 fp32) ----------------
__global__ __launch_bounds__(256) void logm_kernel(const float* __restrict__ m,
                                                   float* __restrict__ lm) {
    const int i = (blockIdx.x * 256 + threadIdx.x) * 4;
    f32x4 v = *(const f32x4*)(m + i);
    f32x4 o;
    #pragma unroll
    for (int j = 0; j < 4; ++j) o[j] = __logf(v[j]);
    *(f32x4*)(lm + i) = o;
}

// ---------------- NT GEMM: C[m,n] = sum_k A[m,k]*W[n,k] + bias[n] ----------------
// A: fp32 (M x 1024) row-major, W: bf16 (1024 x 1024) row-major, N=K=1024.
// nshift==0: fp32 flat output (M x 1024).
// nshift>0 : bf16 head-split output [b][h][n][64], b = m>>nshift, n = m & ((1<<nshift)-1).
__global__ __launch_bounds__(256) void gemm_nt_kernel(
        const float* __restrict__ A, const short* __restrict__ Bw,
        const float* __restrict__ bias, short* __restrict__ outB,
        float* __restrict__ outF, const int nshift) {
    __shared__ short As[128 * 40];   // 128 rows x (32 + 8 pad) bf16
    __shared__ short Bs[128 * 40];

    const int t = threadIdx.x;
    const int lane = t & 63, w = t >> 6;
    const int wr = w >> 1, wc = w & 1;
    const int qd = lane >> 4, c = lane & 15;
    const int tm = blockIdx.y * 128, tn = blockIdx.x * 128;

    f32x4 acc[4][4];
    #pragma unroll
    for (int i = 0; i < 4; ++i)
        #pragma unroll
        for (int j = 0; j < 4; ++j) acc[i][j] = (f32x4){0.f, 0.f, 0.f, 0.f};

    const int sr = t >> 1;          // staging row 0..127
    const int sk = (t & 1) * 16;    // 0 or 16
    const float* aptr = A  + (size_t)(tm + sr) * 1024 + sk;
    const short* bptr = Bw + (size_t)(tn + sr) * 1024 + sk;

    for (int k0 = 0; k0 < 1024; k0 += 32) {
        f32x4 a0 = *(const f32x4*)(aptr + k0);
        f32x4 a1 = *(const f32x4*)(aptr + k0 + 4);
        f32x4 a2 = *(const f32x4*)(aptr + k0 + 8);
        f32x4 a3 = *(const f32x4*)(aptr + k0 + 12);
        bf16x8 b0 = *(const bf16x8*)(bptr + k0);
        bf16x8 b1 = *(const bf16x8*)(bptr + k0 + 8);
        __syncthreads();   // previous iteration's frag reads done
        bf16x8 pa0 = { f2bf(a0[0]), f2bf(a0[1]), f2bf(a0[2]), f2bf(a0[3]),
                       f2bf(a1[0]), f2bf(a1[1]), f2bf(a1[2]), f2bf(a1[3]) };
        bf16x8 pa1 = { f2bf(a2[0]), f2bf(a2[1]), f2bf(a2[2]), f2bf(a2[3]),
                       f2bf(a3[0]), f2bf(a3[1]), f2bf(a3[2]), f2bf(a3[3]) };
        *(bf16x8*)&As[sr * 40 + sk]     = pa0;
        *(bf16x8*)&As[sr * 40 + sk + 8] = pa1;
        *(bf16x8*)&Bs[sr * 40 + sk]     = b0;
        *(bf16x8*)&Bs[sr * 40 + sk + 8] = b1;
        __syncthreads();

        bf16x8 af[4], bf_[4];
        #pragma unroll
        for (int rt = 0; rt < 4; ++rt)
            af[rt] = *(const bf16x8*)&As[(wr * 64 + rt * 16 + c) * 40 + qd * 8];
        #pragma unroll
        for (int ct = 0; ct < 4; ++ct)
            bf_[ct] = *(const bf16x8*)&Bs[(wc * 64 + ct * 16 + c) * 40 + qd * 8];
        #pragma unroll
        for (int rt = 0; rt < 4; ++rt)
            #pragma unroll
            for (int ct = 0; ct < 4; ++ct)
                acc[rt][ct] = MFMA16(af[rt], bf_[ct], acc[rt][ct]);
    }

    float bv[4];
    #pragma unroll
    for (int ct = 0; ct < 4; ++ct) bv[ct] = bias[tn + wc * 64 + ct * 16 + c];

    #pragma unroll
    for (int rt = 0; rt < 4; ++rt) {
        #pragma unroll
        for (int ct = 0; ct < 4; ++ct) {
            const int cg = tn + wc * 64 + ct * 16 + c;
            #pragma unroll
            for (int r = 0; r < 4; ++r) {
                const int rg = tm + wr * 64 + rt * 16 + qd * 4 + r;
                const float v = acc[rt][ct][r] + bv[ct];
                if (nshift == 0) {
                    outF[(size_t)rg * 1024 + cg] = v;
                } else {
                    const int bb = rg >> nshift, n = rg & ((1 << nshift) - 1);
                    const int h = cg >> 6, d = cg & 63;
                    outB[((((size_t)(bb * 16 + h)) << nshift) + n) * 64 + d] = f2bf(v);
                }
            }
        }
    }
}

// ---------------- V transpose per (b,h): [k][d] -> [d][k] ----------------
__global__ __launch_bounds__(256) void vtrans_kernel(const short* __restrict__ Vp,
                                                     short* __restrict__ Vt) {
    __shared__ short T[64 * 72];
    const int bh = blockIdx.y;
    const int k0 = blockIdx.x * 64;
    const int t = threadIdx.x;
    const int r = t >> 2, ch = (t & 3) * 16;
    const short* src = Vp + ((size_t)bh * 2048 + k0 + r) * 64 + ch;
    *(bf16x8*)&T[r * 72 + ch]     = *(const bf16x8*)src;
    *(bf16x8*)&T[r * 72 + ch + 8] = *(const bf16x8*)(src + 8);
    __syncthreads();
    bf16x8 o0, o1;
    #pragma unroll
    for (int i = 0; i < 8; ++i) o0[i] = T[(ch + i) * 72 + r];
    #pragma unroll
    for (int i = 0; i < 8; ++i) o1[i] = T[(ch + 8 + i) * 72 + r];
    short* dst = Vt + ((size_t)bh * 64 + r) * 2048 + k0 + ch;
    *(bf16x8*)dst       = o0;
    *(bf16x8*)(dst + 8) = o1;
}

// ---------------- flash attention, one block per (q-tile, b*h) ----------------
// Computes S^T = K.Q^T tiles so P lands row-contiguous (q x key) in LDS.
__global__ __launch_bounds__(256, 2) void attn_kernel(
        const short* __restrict__ Qp, const short* __restrict__ Kp,
        const short* __restrict__ Vt, const float* __restrict__ logm,
        float* __restrict__ Oflat) {
    __shared__ short UKP[128 * 136];   // Ks (128x72) aliased with Ps (128x136)
    __shared__ short Vs[64 * 136];     // Vt tile, 64 d-rows x (128 + 8 pad)
    __shared__ float Lm[128];
    short* Ks = UKP;
    short* Ps = UKP;

    const int qt = blockIdx.x, bh = blockIdx.y;
    const int b = bh >> 4, h = bh & 15;
    const int t = threadIdx.x, lane = t & 63, w = t >> 6;
    const int qd = lane >> 4, c = lane & 15;

    // Q fragments (B-operand of S^T): lane holds Q[q = w*32+ct*16+c][d = kd*32+qd*8 ..+7]
    bf16x8 qf[2][2];
    #pragma unroll
    for (int ct = 0; ct < 2; ++ct)
        #pragma unroll
        for (int kd = 0; kd < 2; ++kd)
            qf[ct][kd] = *(const bf16x8*)(Qp +
                ((size_t)bh * 1024 + qt * 128 + w * 32 + ct * 16 + c) * 64 + kd * 32 + qd * 8);

    float mo[2] = {-1e30f, -1e30f};
    float li[2] = {0.f, 0.f};
    f32x4 oacc[2][4];
    #pragma unroll
    for (int i = 0; i < 2; ++i)
        #pragma unroll
        for (int j = 0; j < 4; ++j) oacc[i][j] = (f32x4){0.f, 0.f, 0.f, 0.f};

    const short* kg = Kp + ((size_t)bh * 2048 + (t >> 1)) * 64 + (t & 1) * 32;
    const short* vg = Vt + ((size_t)bh * 64 + (t >> 2)) * 2048 + (t & 3) * 32;

    for (int kt = 0; kt < 16; ++kt) {
        // ---- stage K tile (128 keys x 64 d) and V^T tile (64 d x 128 keys) ----
        const short* kp = kg + (size_t)kt * 128 * 64;
        bf16x8 kx0 = *(const bf16x8*)(kp);
        bf16x8 kx1 = *(const bf16x8*)(kp + 8);
        bf16x8 kx2 = *(const bf16x8*)(kp + 16);
        bf16x8 kx3 = *(const bf16x8*)(kp + 24);
        const short* vp = vg + kt * 128;
        bf16x8 vx0 = *(const bf16x8*)(vp);
        bf16x8 vx1 = *(const bf16x8*)(vp + 8);
        bf16x8 vx2 = *(const bf16x8*)(vp + 16);
        bf16x8 vx3 = *(const bf16x8*)(vp + 24);
        float lmv = 0.f;
        if (t < 128) lmv = logm[b * 2048 + kt * 128 + t];

        {
            const int kr = t >> 1, kc = (t & 1) * 32;
            *(bf16x8*)&Ks[kr * 72 + kc]      = kx0;
            *(bf16x8*)&Ks[kr * 72 + kc + 8]  = kx1;
            *(bf16x8*)&Ks[kr * 72 + kc + 16] = kx2;
            *(bf16x8*)&Ks[kr * 72 + kc + 24] = kx3;
            const int vr = t >> 2, vc = (t & 3) * 32;
            *(bf16x8*)&Vs[vr * 136 + vc]      = vx0;
            *(bf16x8*)&Vs[vr * 136 + vc + 8]  = vx1;
            *(bf16x8*)&Vs[vr * 136 + vc + 16] = vx2;
            *(bf16x8*)&Vs[vr * 136 + vc + 24] = vx3;
            if (t < 128) Lm[t] = lmv;
        }
        __syncthreads();

        // ---- S^T = K . Q^T : D[m=key][n=q] ----
        f32x4 s[8][2];
        #pragma unroll
        for (int rt = 0; rt < 8; ++rt) {
            bf16x8 a0 = *(const bf16x8*)&Ks[(rt * 16 + c) * 72 + qd * 8];
            bf16x8 a1 = *(const bf16x8*)&Ks[(rt * 16 + c) * 72 + 32 + qd * 8];
            #pragma unroll
            for (int ct = 0; ct < 2; ++ct) {
                f32x4 z = (f32x4){0.f, 0.f, 0.f, 0.f};
                f32x4 p0 = MFMA16(a0, qf[ct][0], z);
                s[rt][ct] = MFMA16(a1, qf[ct][1], p0);
            }
        }
        __syncthreads();   // all waves done reading Ks before Ps (aliased) is written

        // ---- online softmax over this 128-key tile (per q = column of S^T) ----
        float mt[2] = {-1e30f, -1e30f};
        #pragma unroll
        for (int rt = 0; rt < 8; ++rt) {
            f32x4 lv = *(const f32x4*)&Lm[rt * 16 + qd * 4];
            #pragma unroll
            for (int ct = 0; ct < 2; ++ct)
                #pragma unroll
                for (int r = 0; r < 4; ++r) {
                    float vv = s[rt][ct][r] * 0.125f + lv[r];
                    s[rt][ct][r] = vv;
                    mt[ct] = fmaxf(mt[ct], vv);
                }
        }
        float al[2], snew[2];
        #pragma unroll
        for (int ct = 0; ct < 2; ++ct) {
            mt[ct] = fmaxf(mt[ct], __shfl_xor(mt[ct], 16));
            mt[ct] = fmaxf(mt[ct], __shfl_xor(mt[ct], 32));
            float mn = fmaxf(mo[ct], mt[ct]);
            al[ct] = __expf(mo[ct] - mn);
            mo[ct] = mn;
            snew[ct] = 0.f;
        }
        #pragma unroll
        for (int rt = 0; rt < 8; ++rt) {
            #pragma unroll
            for (int ct = 0; ct < 2; ++ct) {
                short4v pk;
                #pragma unroll
                for (int r = 0; r < 4; ++r) {
                    float p = __expf(s[rt][ct][r] - mo[ct]);
                    snew[ct] += p;
                    pk[r] = f2bf(p);
                }
                *(short4v*)&Ps[(w * 32 + ct * 16 + c) * 136 + rt * 16 + qd * 4] = pk;
            }
        }
        #pragma unroll
        for (int ct = 0; ct < 2; ++ct) {
            snew[ct] += __shfl_xor(snew[ct], 16);
            snew[ct] += __shfl_xor(snew[ct], 32);
            li[ct] = li[ct] * al[ct] + snew[ct];
        }

        // ---- rescale O and accumulate P.V ----
        float alr[2][4];
        #pragma unroll
        for (int rtq = 0; rtq < 2; ++rtq)
            #pragma unroll
            for (int r = 0; r < 4; ++r)
                alr[rtq][r] = __shfl(al[rtq], qd * 4 + r);
        #pragma unroll
        for (int rtq = 0; rtq < 2; ++rtq)
            #pragma unroll
            for (int ct = 0; ct < 4; ++ct)
                #pragma unroll
                for (int r = 0; r < 4; ++r)
                    oacc[rtq][ct][r] *= alr[rtq][r];

        #pragma unroll
        for (int kk = 0; kk < 4; ++kk) {
            bf16x8 pf[2], vf[4];
            #pragma unroll
            for (int rtq = 0; rtq < 2; ++rtq)
                pf[rtq] = *(const bf16x8*)&Ps[(w * 32 + rtq * 16 + c) * 136 + kk * 32 + qd * 8];
            #pragma unroll
            for (int ct = 0; ct < 4; ++ct)
                vf[ct] = *(const bf16x8*)&Vs[(ct * 16 + c) * 136 + kk * 32 + qd * 8];
            #pragma unroll
            for (int rtq = 0; rtq < 2; ++rtq)
                #pragma unroll
                for (int ct = 0; ct < 4; ++ct)
                    oacc[rtq][ct] = MFMA16(pf[rtq], vf[ct], oacc[rtq][ct]);
        }
        __syncthreads();   // protect Ks/Vs/Ps for next staging
    }

    // ---- epilogue: O / l, write fp32 [b*1024+q][h*64+d] ----
    float inv[2][4];
    #pragma unroll
    for (int rtq = 0; rtq < 2; ++rtq)
        #pragma unroll
        for (int r = 0; r < 4; ++r)
            inv[rtq][r] = 1.f / __shfl(li[rtq], qd * 4 + r);
    #pragma unroll
    for (int rtq = 0; rtq < 2; ++rtq)
        #pragma unroll
        for (int ct = 0; ct < 4; ++ct)
            #pragma unroll
            for (int r = 0; r < 4; ++r) {
                const int qg = qt * 128 + w * 32 + rtq * 16 + qd * 4 + r;
                const int e = h * 64 + ct * 16 + c;
                Oflat[((size_t)(b * 1024 + qg)) * 1024 + e] = oacc[rtq][ct][r] * inv[rtq][r];
            }
}

extern "C" void kernel_launch(void* const* d_in, const int* in_sizes, int n_in,
                              void* d_out, int out_size, void* d_ws, size_t ws_size,
                              hipStream_t stream) {
    (void)in_sizes; (void)n_in; (void)out_size; (void)ws_size;
    const float* query = (const float*)d_in[0];
    const float* key   = (const float*)d_in[1];
    const float* value = (const float*)d_in[2];
    const float* mult  = (const float*)d_in[3];
    const float* wq_w  = (const float*)d_in[4];
    const float* wq_b  = (const float*)d_in[5];
    const float* wk_w  = (const float*)d_in[6];
    const float* wk_b  = (const float*)d_in[7];
    const float* wv_w  = (const float*)d_in[8];
    const float* wv_b  = (const float*)d_in[9];
    const float* wo_w  = (const float*)d_in[10];
    const float* wo_b  = (const float*)d_in[11];
    float* out = (float*)d_out;

    char* ws = (char*)d_ws;
    const size_t MB = 1024 * 1024;
    short* wb  = (short*)(ws + 0 * MB);    // wq|wk|wv|wo bf16, 2 MB each
    short* Qp  = (short*)(ws + 8 * MB);    // [b][h][1024][64] bf16, 8 MB
    short* Kp  = (short*)(ws + 16 * MB);   // [b][h][2048][64] bf16, 16 MB
    short* Vp  = (short*)(ws + 32 * MB);   // [b][h][2048][64] bf16, 16 MB
    short* Vt  = (short*)(ws + 48 * MB);   // [b][h][64][2048] bf16, 16 MB
    float* Of  = (float*)(ws + 64 * MB);   // [4096][1024] fp32, 16 MB
    float* lm  = (float*)(ws + 80 * MB);   // [4][2048] fp32

    convw_kernel<<<dim3(1024, 1, 4), 256, 0, stream>>>(wq_w, wk_w, wv_w, wo_w, wb);
    logm_kernel<<<dim3(8), 256, 0, stream>>>(mult, lm);
    gemm_nt_kernel<<<dim3(8, 32), 256, 0, stream>>>(query, wb,           wq_b, Qp, nullptr, 10);
    gemm_nt_kernel<<<dim3(8, 64), 256, 0, stream>>>(key,   wb + 1048576, wk_b, Kp, nullptr, 11);
    gemm_nt_kernel<<<dim3(8, 64), 256, 0, stream>>>(value, wb + 2097152, wv_b, Vp, nullptr, 11);
    vtrans_kernel<<<dim3(32, 64), 256, 0, stream>>>(Vp, Vt);
    attn_kernel<<<dim3(8, 64), 256, 0, stream>>>(Qp, Kp, Vt, lm, Of);
    gemm_nt_kernel<<<dim3(8, 32), 256, 0, stream>>>(Of, wb + 3145728, wo_b, nullptr, out, 0);
}

// Round 2
// 396.087 us; speedup vs baseline: 1.0138x; 1.0138x over previous
//
#include <hip/hip_runtime.h>
#include <stdint.h>
#include <stddef.h>

typedef __attribute__((ext_vector_type(8))) short bf16x8;
typedef __attribute__((ext_vector_type(4))) short short4v;
typedef __attribute__((ext_vector_type(4))) float f32x4;

#define MFMA16(a, b, c) __builtin_amdgcn_mfma_f32_16x16x32_bf16((a), (b), (c), 0, 0, 0)

__device__ __forceinline__ short f2bf(float f) {
    uint32_t u = __builtin_bit_cast(uint32_t, f);
    u = (u + 0x7FFFu + ((u >> 16) & 1u)) >> 16;
    return (short)(uint16_t)u;
}

// async global->LDS, 16B per lane; LDS dest = wave-uniform base + lane*16
__device__ __forceinline__ void gload16(const short* g, short* l) {
    __builtin_amdgcn_global_load_lds(
        (const __attribute__((address_space(1))) unsigned int*)g,
        (__attribute__((address_space(3))) unsigned int*)l, 16, 0, 0);
}

// ---------------- weight fp32 -> bf16 (4 matrices of 1024x1024) ----------------
__global__ __launch_bounds__(256) void convw_kernel(
        const float* __restrict__ w0, const float* __restrict__ w1,
        const float* __restrict__ w2, const float* __restrict__ w3,
        short* __restrict__ dst) {
    const int z = blockIdx.z;
    const float* src = (z == 0) ? w0 : (z == 1) ? w1 : (z == 2) ? w2 : w3;
    const size_t i = ((size_t)blockIdx.x * 256 + threadIdx.x) * 4;
    f32x4 v = *(const f32x4*)(src + i);
    short4v o = { f2bf(v[0]), f2bf(v[1]), f2bf(v[2]), f2bf(v[3]) };
    *(short4v*)(dst + (size_t)z * 1048576 + i) = o;
}

// ---------------- activations fp32 -> bf16 (query 4M, key 8M, value 8M) --------
__global__ __launch_bounds__(256) void convact_kernel(
        const float* __restrict__ q, const float* __restrict__ k,
        const float* __restrict__ v, short* __restrict__ Qa,
        short* __restrict__ Ka, short* __restrict__ Va) {
    const int z = blockIdx.z;
    if (z == 0 && blockIdx.x >= 2048) return;
    const float* src = (z == 0) ? q : (z == 1) ? k : v;
    short* dst = (z == 0) ? Qa : (z == 1) ? Ka : Va;
    const size_t i = ((size_t)blockIdx.x * 256 + threadIdx.x) * 8;
    f32x4 a = *(const f32x4*)(src + i);
    f32x4 b = *(const f32x4*)(src + i + 4);
    short4v o0 = { f2bf(a[0]), f2bf(a[1]), f2bf(a[2]), f2bf(a[3]) };
    short4v o1 = { f2bf(b[0]), f2bf(b[1]), f2bf(b[2]), f2bf(b[3]) };
    *(short4v*)(dst + i)     = o0;
    *(short4v*)(dst + i + 4) = o1;
}

// ---------------- log of multiplicities (4*2048 fp32) ----------------
__global__ __launch_bounds__(256) void logm_kernel(const float* __restrict__ m,
                                                   float* __restrict__ lm) {
    const int i = (blockIdx.x * 256 + threadIdx.x) * 4;
    f32x4 v = *(const f32x4*)(m + i);
    f32x4 o;
    #pragma unroll
    for (int j = 0; j < 4; ++j) o[j] = __logf(v[j]);
    *(f32x4*)(lm + i) = o;
}

// ---------------- bf16 NT GEMM: C[m,n] = sum_k A[m,k]*W[n,k] + bias[n] ---------
// A: bf16 (M x 1024) row-major, W: bf16 (1024 x 1024) row-major.
// m97-style: global_load_lds width-16 staging, 128x128 tile, BK=32.
// LDS layout is 16B-chunked with XOR swizzle pc = qc ^ ((row>>1)&3) so the
// ds_read_b128 fragment reads are bank-conflict-free (8 distinct bank-bases
// per consecutive lane-octet); global_load_lds scatter order picks the
// matching global source per lane.
// mode 0: fp32 flat out (M x 1024).
// mode 1: bf16 head-split out [b][h][n][64]  (n = m & mask, b = m >> nshift)
// mode 2: bf16 head-split TRANSPOSED out [b][h][d][n]  (V -> Vt, 8B stores)
__global__ __launch_bounds__(256) void gemm_bt_kernel(
        const short* __restrict__ A, const short* __restrict__ Bw,
        const float* __restrict__ bias, short* __restrict__ outB,
        float* __restrict__ outF, const int nshift, const int mode) {
    __shared__ short As[128 * 32];   // 8 KB, swizzled chunks, no pad
    __shared__ short Bs[128 * 32];

    const int t = threadIdx.x;
    const int lane = t & 63, w = t >> 6;
    const int wr = w >> 1, wc = w & 1;
    const int qd = lane >> 4, c = lane & 15;
    const int tm = blockIdx.y * 128, tn = blockIdx.x * 128;

    f32x4 acc[4][4];
    #pragma unroll
    for (int i = 0; i < 4; ++i)
        #pragma unroll
        for (int j = 0; j < 4; ++j) acc[i][j] = (f32x4){0.f, 0.f, 0.f, 0.f};

    // staging: wave w covers rows [w*16, w*16+16) and [64+w*16, ...), 1 KB each
    const int r0 = w * 16 + (lane >> 2);
    const int qc = (lane & 3) ^ ((lane >> 3) & 3);   // logical chunk for lane
    const short* ga0 = A  + (size_t)(tm + r0) * 1024 + qc * 8;
    const short* ga1 = ga0 + 64 * 1024;
    const short* gb0 = Bw + (size_t)(tn + r0) * 1024 + qc * 8;
    const short* gb1 = gb0 + 64 * 1024;
    short* la0 = &As[w * 512];
    short* la1 = &As[w * 512 + 2048];
    short* lb0 = &Bs[w * 512];
    short* lb1 = &Bs[w * 512 + 2048];
    const int swz = (qd ^ ((c >> 1) & 3)) * 8;       // physical chunk for reads

    for (int k0 = 0; k0 < 1024; k0 += 32) {
        __syncthreads();    // prior iteration's fragment reads complete
        gload16(ga0 + k0, la0);
        gload16(ga1 + k0, la1);
        gload16(gb0 + k0, lb0);
        gload16(gb1 + k0, lb1);
        __syncthreads();    // compiler drains vmcnt before barrier -> data visible

        bf16x8 af[4], bfr[4];
        #pragma unroll
        for (int rt = 0; rt < 4; ++rt)
            af[rt] = *(const bf16x8*)&As[(wr * 64 + rt * 16 + c) * 32 + swz];
        #pragma unroll
        for (int ct = 0; ct < 4; ++ct)
            bfr[ct] = *(const bf16x8*)&Bs[(wc * 64 + ct * 16 + c) * 32 + swz];
        #pragma unroll
        for (int rt = 0; rt < 4; ++rt)
            #pragma unroll
            for (int ct = 0; ct < 4; ++ct)
                acc[rt][ct] = MFMA16(af[rt], bfr[ct], acc[rt][ct]);
    }

    float bv[4];
    #pragma unroll
    for (int ct = 0; ct < 4; ++ct) bv[ct] = bias[tn + wc * 64 + ct * 16 + c];

    if (mode == 0) {
        #pragma unroll
        for (int rt = 0; rt < 4; ++rt)
            #pragma unroll
            for (int ct = 0; ct < 4; ++ct) {
                const int cg = tn + wc * 64 + ct * 16 + c;
                #pragma unroll
                for (int r = 0; r < 4; ++r) {
                    const int rg = tm + wr * 64 + rt * 16 + qd * 4 + r;
                    outF[(size_t)rg * 1024 + cg] = acc[rt][ct][r] + bv[ct];
                }
            }
    } else if (mode == 1) {
        const int mask = (1 << nshift) - 1;
        #pragma unroll
        for (int rt = 0; rt < 4; ++rt)
            #pragma unroll
            for (int ct = 0; ct < 4; ++ct) {
                const int cg = tn + wc * 64 + ct * 16 + c;
                const int h = cg >> 6, d = cg & 63;
                #pragma unroll
                for (int r = 0; r < 4; ++r) {
                    const int rg = tm + wr * 64 + rt * 16 + qd * 4 + r;
                    const int bb = rg >> nshift, n = rg & mask;
                    outB[((((size_t)(bb * 16 + h)) << nshift) + n) * 64 + d] =
                        f2bf(acc[rt][ct][r] + bv[ct]);
                }
            }
    } else {
        // V -> Vt[bh][d][k]; 4 consecutive r = 4 consecutive k -> 8B store
        const int mask = (1 << nshift) - 1;
        #pragma unroll
        for (int rt = 0; rt < 4; ++rt)
            #pragma unroll
            for (int ct = 0; ct < 4; ++ct) {
                const int cg = tn + wc * 64 + ct * 16 + c;
                const int h = cg >> 6, d = cg & 63;
                const int rg0 = tm + wr * 64 + rt * 16 + qd * 4;
                const int bb = rg0 >> nshift, n = rg0 & mask;
                short4v pk = { f2bf(acc[rt][ct][0] + bv[ct]),
                               f2bf(acc[rt][ct][1] + bv[ct]),
                               f2bf(acc[rt][ct][2] + bv[ct]),
                               f2bf(acc[rt][ct][3] + bv[ct]) };
                *(short4v*)&outB[((((size_t)(bb * 16 + h)) * 64 + d) << nshift) + n] = pk;
            }
    }
}

// ---------------- flash attention, one block per (q-tile, b*h) ----------------
// Computes S^T = K.Q^T tiles so P lands row-contiguous (q x key) in LDS.
// Row strides 76 / 140 shorts (== 6 dwords mod 32): each consecutive 8-lane
// group of a ds_read_b128 hits 8 distinct bank-bases -> no conflicts.
__global__ __launch_bounds__(256, 2) void attn_kernel(
        const short* __restrict__ Qp, const short* __restrict__ Kp,
        const short* __restrict__ Vt, const float* __restrict__ logm,
        short* __restrict__ Ob) {
    __shared__ short UKP[128 * 140];   // Ks (128x76) aliased with Ps (128x140)
    __shared__ short Vs[64 * 140];     // Vt tile, 64 d-rows x (128 + 12 pad)
    __shared__ float Lm[128];
    short* Ks = UKP;
    short* Ps = UKP;

    const int qt = blockIdx.x, bh = blockIdx.y;
    const int b = bh >> 4, h = bh & 15;
    const int t = threadIdx.x, lane = t & 63, w = t >> 6;
    const int qd = lane >> 4, c = lane & 15;

    // Q fragments (B-operand of S^T): lane holds Q[q = w*32+ct*16+c][d = kd*32+qd*8 ..+7]
    bf16x8 qf[2][2];
    #pragma unroll
    for (int ct = 0; ct < 2; ++ct)
        #pragma unroll
        for (int kd = 0; kd < 2; ++kd)
            qf[ct][kd] = *(const bf16x8*)(Qp +
                ((size_t)bh * 1024 + qt * 128 + w * 32 + ct * 16 + c) * 64 + kd * 32 + qd * 8);

    float mo[2] = {-1e30f, -1e30f};
    float li[2] = {0.f, 0.f};
    f32x4 oacc[2][4];
    #pragma unroll
    for (int i = 0; i < 2; ++i)
        #pragma unroll
        for (int j = 0; j < 4; ++j) oacc[i][j] = (f32x4){0.f, 0.f, 0.f, 0.f};

    const short* kg = Kp + ((size_t)bh * 2048 + (t >> 1)) * 64 + (t & 1) * 32;
    const short* vg = Vt + ((size_t)bh * 64 + (t >> 2)) * 2048 + (t & 3) * 32;

    for (int kt = 0; kt < 16; ++kt) {
        const short* kp = kg + (size_t)kt * 128 * 64;
        bf16x8 kx0 = *(const bf16x8*)(kp);
        bf16x8 kx1 = *(const bf16x8*)(kp + 8);
        bf16x8 kx2 = *(const bf16x8*)(kp + 16);
        bf16x8 kx3 = *(const bf16x8*)(kp + 24);
        const short* vp = vg + kt * 128;
        bf16x8 vx0 = *(const bf16x8*)(vp);
        bf16x8 vx1 = *(const bf16x8*)(vp + 8);
        bf16x8 vx2 = *(const bf16x8*)(vp + 16);
        bf16x8 vx3 = *(const bf16x8*)(vp + 24);
        float lmv = 0.f;
        if (t < 128) lmv = logm[b * 2048 + kt * 128 + t];

        {
            const int kr = t >> 1, kc = (t & 1) * 32;
            *(bf16x8*)&Ks[kr * 76 + kc]      = kx0;
            *(bf16x8*)&Ks[kr * 76 + kc + 8]  = kx1;
            *(bf16x8*)&Ks[kr * 76 + kc + 16] = kx2;
            *(bf16x8*)&Ks[kr * 76 + kc + 24] = kx3;
            const int vr = t >> 2, vc = (t & 3) * 32;
            *(bf16x8*)&Vs[vr * 140 + vc]      = vx0;
            *(bf16x8*)&Vs[vr * 140 + vc + 8]  = vx1;
            *(bf16x8*)&Vs[vr * 140 + vc + 16] = vx2;
            *(bf16x8*)&Vs[vr * 140 + vc + 24] = vx3;
            if (t < 128) Lm[t] = lmv;
        }
        __syncthreads();

        // ---- S^T = K . Q^T : D[m=key][n=q] ----
        f32x4 s[8][2];
        #pragma unroll
        for (int rt = 0; rt < 8; ++rt) {
            bf16x8 a0 = *(const bf16x8*)&Ks[(rt * 16 + c) * 76 + qd * 8];
            bf16x8 a1 = *(const bf16x8*)&Ks[(rt * 16 + c) * 76 + 32 + qd * 8];
            #pragma unroll
            for (int ct = 0; ct < 2; ++ct) {
                f32x4 z = (f32x4){0.f, 0.f, 0.f, 0.f};
                f32x4 p0 = MFMA16(a0, qf[ct][0], z);
                s[rt][ct] = MFMA16(a1, qf[ct][1], p0);
            }
        }
        __syncthreads();   // all waves done reading Ks before Ps (aliased) is written

        // ---- online softmax over this 128-key tile (per q = column of S^T) ----
        float mt[2] = {-1e30f, -1e30f};
        #pragma unroll
        for (int rt = 0; rt < 8; ++rt) {
            f32x4 lv = *(const f32x4*)&Lm[rt * 16 + qd * 4];
            #pragma unroll
            for (int ct = 0; ct < 2; ++ct)
                #pragma unroll
                for (int r = 0; r < 4; ++r) {
                    float vv = s[rt][ct][r] * 0.125f + lv[r];
                    s[rt][ct][r] = vv;
                    mt[ct] = fmaxf(mt[ct], vv);
                }
        }
        float al[2], snew[2];
        #pragma unroll
        for (int ct = 0; ct < 2; ++ct) {
            mt[ct] = fmaxf(mt[ct], __shfl_xor(mt[ct], 16));
            mt[ct] = fmaxf(mt[ct], __shfl_xor(mt[ct], 32));
            float mn = fmaxf(mo[ct], mt[ct]);
            al[ct] = __expf(mo[ct] - mn);
            mo[ct] = mn;
            snew[ct] = 0.f;
        }
        #pragma unroll
        for (int rt = 0; rt < 8; ++rt) {
            #pragma unroll
            for (int ct = 0; ct < 2; ++ct) {
                short4v pk;
                #pragma unroll
                for (int r = 0; r < 4; ++r) {
                    float p = __expf(s[rt][ct][r] - mo[ct]);
                    snew[ct] += p;
                    pk[r] = f2bf(p);
                }
                *(short4v*)&Ps[(w * 32 + ct * 16 + c) * 140 + rt * 16 + qd * 4] = pk;
            }
        }
        #pragma unroll
        for (int ct = 0; ct < 2; ++ct) {
            snew[ct] += __shfl_xor(snew[ct], 16);
            snew[ct] += __shfl_xor(snew[ct], 32);
            li[ct] = li[ct] * al[ct] + snew[ct];
        }

        // ---- rescale O and accumulate P.V ----
        float alr[2][4];
        #pragma unroll
        for (int rtq = 0; rtq < 2; ++rtq)
            #pragma unroll
            for (int r = 0; r < 4; ++r)
                alr[rtq][r] = __shfl(al[rtq], qd * 4 + r);
        #pragma unroll
        for (int rtq = 0; rtq < 2; ++rtq)
            #pragma unroll
            for (int ct = 0; ct < 4; ++ct)
                #pragma unroll
                for (int r = 0; r < 4; ++r)
                    oacc[rtq][ct][r] *= alr[rtq][r];

        #pragma unroll
        for (int kk = 0; kk < 4; ++kk) {
            bf16x8 pf[2], vf[4];
            #pragma unroll
            for (int rtq = 0; rtq < 2; ++rtq)
                pf[rtq] = *(const bf16x8*)&Ps[(w * 32 + rtq * 16 + c) * 140 + kk * 32 + qd * 8];
            #pragma unroll
            for (int ct = 0; ct < 4; ++ct)
                vf[ct] = *(const bf16x8*)&Vs[(ct * 16 + c) * 140 + kk * 32 + qd * 8];
            #pragma unroll
            for (int rtq = 0; rtq < 2; ++rtq)
                #pragma unroll
                for (int ct = 0; ct < 4; ++ct)
                    oacc[rtq][ct] = MFMA16(pf[rtq], vf[ct], oacc[rtq][ct]);
        }
        __syncthreads();   // protect Ks/Vs/Ps for next staging
    }

    // ---- epilogue: O / l, write bf16 [b*1024+q][h*64+d] ----
    float inv[2][4];
    #pragma unroll
    for (int rtq = 0; rtq < 2; ++rtq)
        #pragma unroll
        for (int r = 0; r < 4; ++r)
            inv[rtq][r] = 1.f / __shfl(li[rtq], qd * 4 + r);
    #pragma unroll
    for (int rtq = 0; rtq < 2; ++rtq)
        #pragma unroll
        for (int ct = 0; ct < 4; ++ct)
            #pragma unroll
            for (int r = 0; r < 4; ++r) {
                const int qg = qt * 128 + w * 32 + rtq * 16 + qd * 4 + r;
                const int e = h * 64 + ct * 16 + c;
                Ob[((size_t)(b * 1024 + qg)) * 1024 + e] = f2bf(oacc[rtq][ct][r] * inv[rtq][r]);
            }
}

extern "C" void kernel_launch(void* const* d_in, const int* in_sizes, int n_in,
                              void* d_out, int out_size, void* d_ws, size_t ws_size,
                              hipStream_t stream) {
    (void)in_sizes; (void)n_in; (void)out_size; (void)ws_size;
    const float* query = (const float*)d_in[0];
    const float* key   = (const float*)d_in[1];
    const float* value = (const float*)d_in[2];
    const float* mult  = (const float*)d_in[3];
    const float* wq_w  = (const float*)d_in[4];
    const float* wq_b  = (const float*)d_in[5];
    const float* wk_w  = (const float*)d_in[6];
    const float* wk_b  = (const float*)d_in[7];
    const float* wv_w  = (const float*)d_in[8];
    const float* wv_b  = (const float*)d_in[9];
    const float* wo_w  = (const float*)d_in[10];
    const float* wo_b  = (const float*)d_in[11];
    float* out = (float*)d_out;

    // Workspace layout with liveness overlap (72.04 MB total):
    //   wb  0-8    weights bf16 (live all)
    //   Qa  8-16   dead after Q GEMM ┐
    //   Ka  16-32  dead after K GEMM ┴-> Vt 8-24 (written by V GEMM)
    //   Va  32-48  dead after V GEMM --> Ob 32-40 (written by attn)
    //   Qp  48-56, Kp 56-72, lm 72+
    char* ws = (char*)d_ws;
    const size_t MB = 1024 * 1024;
    short* wb = (short*)(ws + 0 * MB);
    short* Qa = (short*)(ws + 8 * MB);
    short* Ka = (short*)(ws + 16 * MB);
    short* Va = (short*)(ws + 32 * MB);
    short* Vt = (short*)(ws + 8 * MB);
    short* Ob = (short*)(ws + 32 * MB);
    short* Qp = (short*)(ws + 48 * MB);
    short* Kp = (short*)(ws + 56 * MB);
    float* lm = (float*)(ws + 72 * MB);

    convw_kernel<<<dim3(1024, 1, 4), 256, 0, stream>>>(wq_w, wk_w, wv_w, wo_w, wb);
    logm_kernel<<<dim3(8), 256, 0, stream>>>(mult, lm);
    convact_kernel<<<dim3(4096, 1, 3), 256, 0, stream>>>(query, key, value, Qa, Ka, Va);
    gemm_bt_kernel<<<dim3(8, 32), 256, 0, stream>>>(Qa, wb,           wq_b, Qp, nullptr, 10, 1);
    gemm_bt_kernel<<<dim3(8, 64), 256, 0, stream>>>(Ka, wb + 1048576, wk_b, Kp, nullptr, 11, 1);
    gemm_bt_kernel<<<dim3(8, 64), 256, 0, stream>>>(Va, wb + 2097152, wv_b, Vt, nullptr, 11, 2);
    attn_kernel<<<dim3(8, 64), 256, 0, stream>>>(Qp, Kp, Vt, lm, Ob);
    gemm_bt_kernel<<<dim3(8, 32), 256, 0, stream>>>(Ob, wb + 3145728, wo_b, nullptr, out, 0, 0);
}

// Round 3
// 297.439 us; speedup vs baseline: 1.3500x; 1.3317x over previous
//
#include <hip/hip_runtime.h>
#include <hip/hip_bf16.h>
#include <stdint.h>
#include <stddef.h>

typedef __attribute__((ext_vector_type(8))) short bf16x8;
typedef __attribute__((ext_vector_type(4))) short short4v;
typedef __attribute__((ext_vector_type(4))) float f32x4;
typedef __attribute__((ext_vector_type(2))) uint32_t u32x2;
typedef __attribute__((ext_vector_type(4))) uint32_t u32x4;

#define MFMA16(a, b, c) __builtin_amdgcn_mfma_f32_16x16x32_bf16((a), (b), (c), 0, 0, 0)

__device__ __forceinline__ short f2bf(float f) {
    uint32_t u = __builtin_bit_cast(uint32_t, f);
    u = (u + 0x7FFFu + ((u >> 16) & 1u)) >> 16;
    return (short)(uint16_t)u;
}

// pack two fp32 -> two bf16 (RNE) in one v_cvt_pk_bf16_f32 when available
__device__ __forceinline__ uint32_t pkbf(float a, float b) {
#if __has_builtin(__builtin_amdgcn_cvt_pk_bf16_f32)
    auto r = __builtin_amdgcn_cvt_pk_bf16_f32(a, b);
    return __builtin_bit_cast(uint32_t, r);
#else
    return (uint32_t)(uint16_t)f2bf(a) | ((uint32_t)(uint16_t)f2bf(b) << 16);
#endif
}

__device__ __forceinline__ float fexp2(float x) {
#if __has_builtin(__builtin_amdgcn_exp2f)
    return __builtin_amdgcn_exp2f(x);
#else
    return exp2f(x);
#endif
}

// async global->LDS, 16B per lane; LDS dest = wave-uniform base + lane*16
__device__ __forceinline__ void gload16(const short* g, short* l) {
    __builtin_amdgcn_global_load_lds(
        (const __attribute__((address_space(1))) unsigned int*)g,
        (__attribute__((address_space(3))) unsigned int*)l, 16, 0, 0);
}

// ---------------- prep: all fp32->bf16 conversions + log2(mult), one dispatch --
// z 0..3: weights (1M elems each); z 4: query (4M); z 5: key (8M); z 6: value (8M);
// z 7: log2 of multiplicities (8K).
__global__ __launch_bounds__(256) void prep_kernel(
        const float* __restrict__ w0, const float* __restrict__ w1,
        const float* __restrict__ w2, const float* __restrict__ w3,
        const float* __restrict__ q, const float* __restrict__ k,
        const float* __restrict__ v, const float* __restrict__ m,
        short* __restrict__ wb, short* __restrict__ Qa,
        short* __restrict__ Ka, short* __restrict__ Va,
        float* __restrict__ lm) {
    const int z = blockIdx.z, bx = blockIdx.x;
    if (z == 7) {
        if (bx >= 4) return;
        const int i = (bx * 256 + threadIdx.x) * 8;
        f32x4 a = *(const f32x4*)(m + i);
        f32x4 b = *(const f32x4*)(m + i + 4);
        f32x4 oa, ob;
        #pragma unroll
        for (int j = 0; j < 4; ++j) { oa[j] = __log2f(a[j]); ob[j] = __log2f(b[j]); }
        *(f32x4*)(lm + i) = oa;
        *(f32x4*)(lm + i + 4) = ob;
        return;
    }
    const float* src;
    short* dst;
    int nb;
    if (z < 4) {
        src = (z == 0) ? w0 : (z == 1) ? w1 : (z == 2) ? w2 : w3;
        dst = wb + (size_t)z * 1048576;
        nb = 512;
    } else if (z == 4) { src = q; dst = Qa; nb = 2048; }
    else if (z == 5)   { src = k; dst = Ka; nb = 4096; }
    else               { src = v; dst = Va; nb = 4096; }
    if (bx >= nb) return;
    const size_t i = ((size_t)bx * 256 + threadIdx.x) * 8;
    f32x4 a = *(const f32x4*)(src + i);
    f32x4 b = *(const f32x4*)(src + i + 4);
    u32x4 o = { pkbf(a[0], a[1]), pkbf(a[2], a[3]), pkbf(b[0], b[1]), pkbf(b[2], b[3]) };
    *(u32x4*)(dst + i) = o;
}

// ---- shared GEMM core pieces (128x128 tile, BK=32, XOR-swizzled LDS chunks) ----
// Proven correct in R2. Row stride in LDS = 32 shorts (64B, 16B-aligned chunks).

// ---------------- merged Q+K projection GEMM ----------------
// y<32: Q rows (A=Qa, W=wb, out Qp nshift=10); y>=32: K rows (A=Ka, W=wb+1M, Kp, 11)
__global__ __launch_bounds__(256) void gemm_qk_kernel(
        const short* __restrict__ Qa, const short* __restrict__ Ka,
        const short* __restrict__ wb, const float* __restrict__ wq_b,
        const float* __restrict__ wk_b, short* __restrict__ Qp,
        short* __restrict__ Kp) {
    __shared__ short As[128 * 32];
    __shared__ short Bs[128 * 32];

    const int y = blockIdx.y;
    const short* A; const short* W; const float* bias; short* out; int nshift, tm;
    if (y < 32) { A = Qa; W = wb;           bias = wq_b; out = Qp; nshift = 10; tm = y * 128; }
    else        { A = Ka; W = wb + 1048576; bias = wk_b; out = Kp; nshift = 11; tm = (y - 32) * 128; }

    const int t = threadIdx.x, lane = t & 63, w = t >> 6;
    const int wr = w >> 1, wc = w & 1;
    const int qd = lane >> 4, c = lane & 15;
    const int tn = blockIdx.x * 128;

    f32x4 acc[4][4];
    #pragma unroll
    for (int i = 0; i < 4; ++i)
        #pragma unroll
        for (int j = 0; j < 4; ++j) acc[i][j] = (f32x4){0.f, 0.f, 0.f, 0.f};

    const int r0 = w * 16 + (lane >> 2);
    const int qc = (lane & 3) ^ ((lane >> 3) & 3);
    const short* ga0 = A + (size_t)(tm + r0) * 1024 + qc * 8;
    const short* ga1 = ga0 + 64 * 1024;
    const short* gb0 = W + (size_t)(tn + r0) * 1024 + qc * 8;
    const short* gb1 = gb0 + 64 * 1024;
    short* la0 = &As[w * 512];
    short* la1 = &As[w * 512 + 2048];
    short* lb0 = &Bs[w * 512];
    short* lb1 = &Bs[w * 512 + 2048];
    const int swz = (qd ^ ((c >> 1) & 3)) * 8;

    for (int k0 = 0; k0 < 1024; k0 += 32) {
        __syncthreads();
        gload16(ga0 + k0, la0);
        gload16(ga1 + k0, la1);
        gload16(gb0 + k0, lb0);
        gload16(gb1 + k0, lb1);
        __syncthreads();
        bf16x8 af[4], bfr[4];
        #pragma unroll
        for (int rt = 0; rt < 4; ++rt)
            af[rt] = *(const bf16x8*)&As[(wr * 64 + rt * 16 + c) * 32 + swz];
        #pragma unroll
        for (int ct = 0; ct < 4; ++ct)
            bfr[ct] = *(const bf16x8*)&Bs[(wc * 64 + ct * 16 + c) * 32 + swz];
        #pragma unroll
        for (int rt = 0; rt < 4; ++rt)
            #pragma unroll
            for (int ct = 0; ct < 4; ++ct)
                acc[rt][ct] = MFMA16(af[rt], bfr[ct], acc[rt][ct]);
    }

    float bv[4];
    #pragma unroll
    for (int ct = 0; ct < 4; ++ct) bv[ct] = bias[tn + wc * 64 + ct * 16 + c];

    const int mask = (1 << nshift) - 1;
    #pragma unroll
    for (int rt = 0; rt < 4; ++rt)
        #pragma unroll
        for (int ct = 0; ct < 4; ++ct) {
            const int cg = tn + wc * 64 + ct * 16 + c;
            const int h = cg >> 6, d = cg & 63;
            #pragma unroll
            for (int r = 0; r < 4; ++r) {
                const int rg = tm + wr * 64 + rt * 16 + qd * 4 + r;
                const int bb = rg >> nshift, n = rg & mask;
                out[((((size_t)(bb * 16 + h)) << nshift) + n) * 64 + d] =
                    f2bf(acc[rt][ct][r] + bv[ct]);
            }
        }
}

// ---------------- V projection GEMM, transposed epilogue -> Vt[bh][d][k] -------
__global__ __launch_bounds__(256) void gemm_v_kernel(
        const short* __restrict__ Va, const short* __restrict__ W,
        const float* __restrict__ bias, short* __restrict__ Vt) {
    __shared__ short As[128 * 32];
    __shared__ short Bs[128 * 32];

    const int t = threadIdx.x, lane = t & 63, w = t >> 6;
    const int wr = w >> 1, wc = w & 1;
    const int qd = lane >> 4, c = lane & 15;
    const int tm = blockIdx.y * 128, tn = blockIdx.x * 128;

    f32x4 acc[4][4];
    #pragma unroll
    for (int i = 0; i < 4; ++i)
        #pragma unroll
        for (int j = 0; j < 4; ++j) acc[i][j] = (f32x4){0.f, 0.f, 0.f, 0.f};

    const int r0 = w * 16 + (lane >> 2);
    const int qc = (lane & 3) ^ ((lane >> 3) & 3);
    const short* ga0 = Va + (size_t)(tm + r0) * 1024 + qc * 8;
    const short* ga1 = ga0 + 64 * 1024;
    const short* gb0 = W + (size_t)(tn + r0) * 1024 + qc * 8;
    const short* gb1 = gb0 + 64 * 1024;
    short* la0 = &As[w * 512];
    short* la1 = &As[w * 512 + 2048];
    short* lb0 = &Bs[w * 512];
    short* lb1 = &Bs[w * 512 + 2048];
    const int swz = (qd ^ ((c >> 1) & 3)) * 8;

    for (int k0 = 0; k0 < 1024; k0 += 32) {
        __syncthreads();
        gload16(ga0 + k0, la0);
        gload16(ga1 + k0, la1);
        gload16(gb0 + k0, lb0);
        gload16(gb1 + k0, lb1);
        __syncthreads();
        bf16x8 af[4], bfr[4];
        #pragma unroll
        for (int rt = 0; rt < 4; ++rt)
            af[rt] = *(const bf16x8*)&As[(wr * 64 + rt * 16 + c) * 32 + swz];
        #pragma unroll
        for (int ct = 0; ct < 4; ++ct)
            bfr[ct] = *(const bf16x8*)&Bs[(wc * 64 + ct * 16 + c) * 32 + swz];
        #pragma unroll
        for (int rt = 0; rt < 4; ++rt)
            #pragma unroll
            for (int ct = 0; ct < 4; ++ct)
                acc[rt][ct] = MFMA16(af[rt], bfr[ct], acc[rt][ct]);
    }

    float bv[4];
    #pragma unroll
    for (int ct = 0; ct < 4; ++ct) bv[ct] = bias[tn + wc * 64 + ct * 16 + c];

    // Vt[bh][d][k]: 4 consecutive acc elems = 4 consecutive k -> 8B store
    #pragma unroll
    for (int rt = 0; rt < 4; ++rt)
        #pragma unroll
        for (int ct = 0; ct < 4; ++ct) {
            const int cg = tn + wc * 64 + ct * 16 + c;
            const int h = cg >> 6, d = cg & 63;
            const int rg0 = tm + wr * 64 + rt * 16 + qd * 4;
            const int bb = rg0 >> 11, n = rg0 & 2047;
            u32x2 pk = { pkbf(acc[rt][ct][0] + bv[ct], acc[rt][ct][1] + bv[ct]),
                         pkbf(acc[rt][ct][2] + bv[ct], acc[rt][ct][3] + bv[ct]) };
            *(u32x2*)&Vt[((((size_t)(bb * 16 + h)) * 64 + d) << 11) + n] = pk;
        }
}

// ---------------- O projection GEMM: 128x64 tile, fp32 out ----------------
__global__ __launch_bounds__(256) void gemm_o_kernel(
        const short* __restrict__ Ob, const short* __restrict__ W,
        const float* __restrict__ bias, float* __restrict__ out) {
    __shared__ short As[128 * 32];
    __shared__ short Bs[64 * 32];

    const int t = threadIdx.x, lane = t & 63, w = t >> 6;
    const int wr = w >> 1, wc = w & 1;
    const int qd = lane >> 4, c = lane & 15;
    const int tm = blockIdx.y * 128, tn = blockIdx.x * 64;

    f32x4 acc[4][2];
    #pragma unroll
    for (int i = 0; i < 4; ++i)
        #pragma unroll
        for (int j = 0; j < 2; ++j) acc[i][j] = (f32x4){0.f, 0.f, 0.f, 0.f};

    const int r0 = w * 16 + (lane >> 2);
    const int qc = (lane & 3) ^ ((lane >> 3) & 3);
    const short* ga0 = Ob + (size_t)(tm + r0) * 1024 + qc * 8;
    const short* ga1 = ga0 + 64 * 1024;
    const short* gb0 = W + (size_t)(tn + r0) * 1024 + qc * 8;
    short* la0 = &As[w * 512];
    short* la1 = &As[w * 512 + 2048];
    short* lb0 = &Bs[w * 512];
    const int swz = (qd ^ ((c >> 1) & 3)) * 8;

    for (int k0 = 0; k0 < 1024; k0 += 32) {
        __syncthreads();
        gload16(ga0 + k0, la0);
        gload16(ga1 + k0, la1);
        gload16(gb0 + k0, lb0);
        __syncthreads();
        bf16x8 af[4], bfr[2];
        #pragma unroll
        for (int rt = 0; rt < 4; ++rt)
            af[rt] = *(const bf16x8*)&As[(wr * 64 + rt * 16 + c) * 32 + swz];
        #pragma unroll
        for (int ct = 0; ct < 2; ++ct)
            bfr[ct] = *(const bf16x8*)&Bs[(wc * 32 + ct * 16 + c) * 32 + swz];
        #pragma unroll
        for (int rt = 0; rt < 4; ++rt)
            #pragma unroll
            for (int ct = 0; ct < 2; ++ct)
                acc[rt][ct] = MFMA16(af[rt], bfr[ct], acc[rt][ct]);
    }

    float bv[2];
    #pragma unroll
    for (int ct = 0; ct < 2; ++ct) bv[ct] = bias[tn + wc * 32 + ct * 16 + c];

    #pragma unroll
    for (int rt = 0; rt < 4; ++rt)
        #pragma unroll
        for (int ct = 0; ct < 2; ++ct) {
            const int cg = tn + wc * 32 + ct * 16 + c;
            #pragma unroll
            for (int r = 0; r < 4; ++r) {
                const int rg = tm + wr * 64 + rt * 16 + qd * 4 + r;
                out[(size_t)rg * 1024 + cg] = acc[rt][ct][r] + bv[ct];
            }
        }
}

// ---------------- flash attention, one block per (q-tile, b*h) ----------------
// S^T = K.Q^T so P lands row-contiguous in LDS. Strides 72/136 shorts: rows
// stay 16B-aligned (b128 ops unsplit); residual conflicts are 2-way (free).
// Softmax in exp2 domain; bf16 packing via v_cvt_pk_bf16_f32.
__global__ __launch_bounds__(256, 2) void attn_kernel(
        const short* __restrict__ Qp, const short* __restrict__ Kp,
        const short* __restrict__ Vt, const float* __restrict__ logm,
        short* __restrict__ Ob) {
    __shared__ short UKP[128 * 136];   // Ks (128x72) aliased with Ps (128x136)
    __shared__ short Vs[64 * 136];
    __shared__ float Lm[128];
    short* Ks = UKP;
    short* Ps = UKP;

    const int qt = blockIdx.x, bh = blockIdx.y;
    const int b = bh >> 4;
    const int t = threadIdx.x, lane = t & 63, w = t >> 6;
    const int qd = lane >> 4, c = lane & 15;
    const float SC = 0.18033688011112042f;   // 0.125 * log2(e)

    bf16x8 qf[2][2];
    #pragma unroll
    for (int ct = 0; ct < 2; ++ct)
        #pragma unroll
        for (int kd = 0; kd < 2; ++kd)
            qf[ct][kd] = *(const bf16x8*)(Qp +
                ((size_t)bh * 1024 + qt * 128 + w * 32 + ct * 16 + c) * 64 + kd * 32 + qd * 8);

    float mo[2] = {-1e30f, -1e30f};
    float li[2] = {0.f, 0.f};
    f32x4 oacc[2][4];
    #pragma unroll
    for (int i = 0; i < 2; ++i)
        #pragma unroll
        for (int j = 0; j < 4; ++j) oacc[i][j] = (f32x4){0.f, 0.f, 0.f, 0.f};

    const short* kg = Kp + ((size_t)bh * 2048 + (t >> 1)) * 64 + (t & 1) * 32;
    const short* vg = Vt + ((size_t)bh * 64 + (t >> 2)) * 2048 + (t & 3) * 32;

    for (int kt = 0; kt < 16; ++kt) {
        const short* kp = kg + (size_t)kt * 128 * 64;
        bf16x8 kx0 = *(const bf16x8*)(kp);
        bf16x8 kx1 = *(const bf16x8*)(kp + 8);
        bf16x8 kx2 = *(const bf16x8*)(kp + 16);
        bf16x8 kx3 = *(const bf16x8*)(kp + 24);
        const short* vp = vg + kt * 128;
        bf16x8 vx0 = *(const bf16x8*)(vp);
        bf16x8 vx1 = *(const bf16x8*)(vp + 8);
        bf16x8 vx2 = *(const bf16x8*)(vp + 16);
        bf16x8 vx3 = *(const bf16x8*)(vp + 24);
        float lmv = 0.f;
        if (t < 128) lmv = logm[b * 2048 + kt * 128 + t];

        {
            const int kr = t >> 1, kc = (t & 1) * 32;
            *(bf16x8*)&Ks[kr * 72 + kc]      = kx0;
            *(bf16x8*)&Ks[kr * 72 + kc + 8]  = kx1;
            *(bf16x8*)&Ks[kr * 72 + kc + 16] = kx2;
            *(bf16x8*)&Ks[kr * 72 + kc + 24] = kx3;
            const int vr = t >> 2, vc = (t & 3) * 32;
            *(bf16x8*)&Vs[vr * 136 + vc]      = vx0;
            *(bf16x8*)&Vs[vr * 136 + vc + 8]  = vx1;
            *(bf16x8*)&Vs[vr * 136 + vc + 16] = vx2;
            *(bf16x8*)&Vs[vr * 136 + vc + 24] = vx3;
            if (t < 128) Lm[t] = lmv;
        }
        __syncthreads();

        // ---- S^T = K . Q^T ----
        f32x4 s[8][2];
        #pragma unroll
        for (int rt = 0; rt < 8; ++rt) {
            bf16x8 a0 = *(const bf16x8*)&Ks[(rt * 16 + c) * 72 + qd * 8];
            bf16x8 a1 = *(const bf16x8*)&Ks[(rt * 16 + c) * 72 + 32 + qd * 8];
            #pragma unroll
            for (int ct = 0; ct < 2; ++ct) {
                f32x4 z = (f32x4){0.f, 0.f, 0.f, 0.f};
                f32x4 p0 = MFMA16(a0, qf[ct][0], z);
                s[rt][ct] = MFMA16(a1, qf[ct][1], p0);
            }
        }
        __syncthreads();   // Ks reads complete before Ps (aliased) is written

        // ---- online softmax (exp2 domain) ----
        float mt[2] = {-1e30f, -1e30f};
        #pragma unroll
        for (int rt = 0; rt < 8; ++rt) {
            f32x4 lv = *(const f32x4*)&Lm[rt * 16 + qd * 4];
            #pragma unroll
            for (int ct = 0; ct < 2; ++ct)
                #pragma unroll
                for (int r = 0; r < 4; ++r) {
                    float vv = s[rt][ct][r] * SC + lv[r];
                    s[rt][ct][r] = vv;
                    mt[ct] = fmaxf(mt[ct], vv);
                }
        }
        float al[2], snew[2];
        #pragma unroll
        for (int ct = 0; ct < 2; ++ct) {
            mt[ct] = fmaxf(mt[ct], __shfl_xor(mt[ct], 16));
            mt[ct] = fmaxf(mt[ct], __shfl_xor(mt[ct], 32));
            float mn = fmaxf(mo[ct], mt[ct]);
            al[ct] = fexp2(mo[ct] - mn);
            mo[ct] = mn;
            snew[ct] = 0.f;
        }
        #pragma unroll
        for (int rt = 0; rt < 8; ++rt) {
            #pragma unroll
            for (int ct = 0; ct < 2; ++ct) {
                float p0 = fexp2(s[rt][ct][0] - mo[ct]);
                float p1 = fexp2(s[rt][ct][1] - mo[ct]);
                float p2 = fexp2(s[rt][ct][2] - mo[ct]);
                float p3 = fexp2(s[rt][ct][3] - mo[ct]);
                snew[ct] += (p0 + p1) + (p2 + p3);
                u32x2 pk = { pkbf(p0, p1), pkbf(p2, p3) };
                *(u32x2*)&Ps[(w * 32 + ct * 16 + c) * 136 + rt * 16 + qd * 4] = pk;
            }
        }
        #pragma unroll
        for (int ct = 0; ct < 2; ++ct) {
            snew[ct] += __shfl_xor(snew[ct], 16);
            snew[ct] += __shfl_xor(snew[ct], 32);
            li[ct] = li[ct] * al[ct] + snew[ct];
        }

        // ---- rescale O, accumulate P.V ----
        float alr[2][4];
        #pragma unroll
        for (int rtq = 0; rtq < 2; ++rtq)
            #pragma unroll
            for (int r = 0; r < 4; ++r)
                alr[rtq][r] = __shfl(al[rtq], qd * 4 + r);
        #pragma unroll
        for (int rtq = 0; rtq < 2; ++rtq)
            #pragma unroll
            for (int ct = 0; ct < 4; ++ct)
                #pragma unroll
                for (int r = 0; r < 4; ++r)
                    oacc[rtq][ct][r] *= alr[rtq][r];

        #pragma unroll
        for (int kk = 0; kk < 4; ++kk) {
            bf16x8 pf[2], vf[4];
            #pragma unroll
            for (int rtq = 0; rtq < 2; ++rtq)
                pf[rtq] = *(const bf16x8*)&Ps[(w * 32 + rtq * 16 + c) * 136 + kk * 32 + qd * 8];
            #pragma unroll
            for (int ct = 0; ct < 4; ++ct)
                vf[ct] = *(const bf16x8*)&Vs[(ct * 16 + c) * 136 + kk * 32 + qd * 8];
            #pragma unroll
            for (int rtq = 0; rtq < 2; ++rtq)
                #pragma unroll
                for (int ct = 0; ct < 4; ++ct)
                    oacc[rtq][ct] = MFMA16(pf[rtq], vf[ct], oacc[rtq][ct]);
        }
        __syncthreads();
    }

    // ---- epilogue: O / l, bf16 out [b*1024+q][h*64+d] ----
    const int h = bh & 15;
    float inv[2][4];
    #pragma unroll
    for (int rtq = 0; rtq < 2; ++rtq)
        #pragma unroll
        for (int r = 0; r < 4; ++r)
            inv[rtq][r] = 1.f / __shfl(li[rtq], qd * 4 + r);
    #pragma unroll
    for (int rtq = 0; rtq < 2; ++rtq)
        #pragma unroll
        for (int ct = 0; ct < 4; ++ct)
            #pragma unroll
            for (int r = 0; r < 4; ++r) {
                const int qg = qt * 128 + w * 32 + rtq * 16 + qd * 4 + r;
                const int e = h * 64 + ct * 16 + c;
                Ob[((size_t)(b * 1024 + qg)) * 1024 + e] = f2bf(oacc[rtq][ct][r] * inv[rtq][r]);
            }
}

extern "C" void kernel_launch(void* const* d_in, const int* in_sizes, int n_in,
                              void* d_out, int out_size, void* d_ws, size_t ws_size,
                              hipStream_t stream) {
    (void)in_sizes; (void)n_in; (void)out_size; (void)ws_size;
    const float* query = (const float*)d_in[0];
    const float* key   = (const float*)d_in[1];
    const float* value = (const float*)d_in[2];
    const float* mult  = (const float*)d_in[3];
    const float* wq_w  = (const float*)d_in[4];
    const float* wq_b  = (const float*)d_in[5];
    const float* wk_w  = (const float*)d_in[6];
    const float* wk_b  = (const float*)d_in[7];
    const float* wv_w  = (const float*)d_in[8];
    const float* wv_b  = (const float*)d_in[9];
    const float* wo_w  = (const float*)d_in[10];
    const float* wo_b  = (const float*)d_in[11];
    float* out = (float*)d_out;

    // Workspace (72.04 MB), liveness-overlapped:
    //   wb 0-8 | Qa 8-16, Ka 16-32 (dead after gemm_qk) -> Vt 8-24
    //   Va 32-48 (dead after gemm_v) -> Ob 32-40 | Qp 48-56 | Kp 56-72 | lm 72+
    char* ws = (char*)d_ws;
    const size_t MB = 1024 * 1024;
    short* wb = (short*)(ws + 0 * MB);
    short* Qa = (short*)(ws + 8 * MB);
    short* Ka = (short*)(ws + 16 * MB);
    short* Va = (short*)(ws + 32 * MB);
    short* Vt = (short*)(ws + 8 * MB);
    short* Ob = (short*)(ws + 32 * MB);
    short* Qp = (short*)(ws + 48 * MB);
    short* Kp = (short*)(ws + 56 * MB);
    float* lm = (float*)(ws + 72 * MB);

    prep_kernel<<<dim3(4096, 1, 8), 256, 0, stream>>>(
        wq_w, wk_w, wv_w, wo_w, query, key, value, mult, wb, Qa, Ka, Va, lm);
    gemm_qk_kernel<<<dim3(8, 96), 256, 0, stream>>>(Qa, Ka, wb, wq_b, wk_b, Qp, Kp);
    gemm_v_kernel<<<dim3(8, 64), 256, 0, stream>>>(Va, wb + 2097152, wv_b, Vt);
    attn_kernel<<<dim3(8, 64), 256, 0, stream>>>(Qp, Kp, Vt, lm, Ob);
    gemm_o_kernel<<<dim3(16, 32), 256, 0, stream>>>(Ob, wb + 3145728, wo_b, out);
}